// Round 8
// baseline (5290.372 us; speedup 1.0000x reference)
//
#include <hip/hip_runtime.h>

namespace {

constexpr int N_NODES = 2048;
constexpr int IN_DIM  = 256;
constexpr int HEADS   = 6;
constexpr int HD      = 64;
constexpr int OUT_DIM = HEADS * HD;   // 384

// ---------------------------------------------------------------------------
// Kernel 1: projections + attention-vector dots.
// grid (512, 6, 2), block 256 = 4 waves; wave w handles node blockIdx.x*4+w.
// ---------------------------------------------------------------------------
__global__ __launch_bounds__(256) void qk_proj(
    const float* __restrict__ hmat, const float* __restrict__ Wsrc,
    const float* __restrict__ Wdst, const float* __restrict__ a,
    float* __restrict__ Qw, float* __restrict__ Kw,
    float* __restrict__ qaw, float* __restrict__ kaw)
{
  const int lane = threadIdx.x & 63;
  const int w    = threadIdx.x >> 6;
  const int i    = blockIdx.x * 4 + w;
  const int head = blockIdx.y;
  const int z    = blockIdx.z;
  const float* __restrict__ W = (z ? Wdst : Wsrc) + (size_t)head * IN_DIM * HD;
  const float* __restrict__ hrow = hmat + (size_t)i * IN_DIM;

  float a0 = 0.f, a1 = 0.f, a2 = 0.f, a3 = 0.f;
  #pragma unroll 4
  for (int k = 0; k < IN_DIM; k += 4) {
    const float4 hv = *(const float4*)&hrow[k];
    a0 = fmaf(hv.x, W[(k + 0) * HD + lane], a0);
    a1 = fmaf(hv.y, W[(k + 1) * HD + lane], a1);
    a2 = fmaf(hv.z, W[(k + 2) * HD + lane], a2);
    a3 = fmaf(hv.w, W[(k + 3) * HD + lane], a3);
  }
  const float acc = (a0 + a1) + (a2 + a3);
  (z ? Kw : Qw)[((size_t)head * N_NODES + i) * HD + lane] = acc;

  float rsum = acc * a[head * HD + lane];
  #pragma unroll
  for (int off = 32; off; off >>= 1) rsum += __shfl_xor(rsum, off);
  if (lane == 0) (z ? kaw : qaw)[head * N_NODES + i] = 0.6f * rsum;
}

// ---------------------------------------------------------------------------
// Kernel 2: fused scores + masked softmax + attn_mean + PV + h'.
// grid 256 x 512 threads (8 waves). LDS = 133 KB -> 1 block/CU regardless of
// VGPRs, so NO min-waves launch_bounds arg: round 6/7 used (512,2) -> VGPR
// capped at exactly 128 -> spill scratch traffic (2.2 GB fetch / 3.3 GB
// write per dispatch, writes > all legitimate write sources by 30x).
//  pass1 : ONE K-row per thread (4 passes of 512 rows): acc[8] not acc[8][2],
//          lanes read consecutive 256 B rows sequentially (L1-sector reuse).
//  pass2a: exp in place + row sums -> invs.         [as measured]
//  attn  : RMW on global out_attn, own slots.       [as measured]
//  PV    : LDS-tiled K, wave j-slices, 0 conflicts. [as measured, round 7]
// ---------------------------------------------------------------------------
__global__ __launch_bounds__(512) void gat_fused(
    const float* __restrict__ Qw, const float* __restrict__ Kw,
    const float* __restrict__ qaw, const float* __restrict__ kaw,
    const float* __restrict__ a, const float* __restrict__ adj,
    const float* __restrict__ bias, float* __restrict__ out_h,
    float* __restrict__ out_attn)
{
  __shared__ float e_lds[8][N_NODES];             // 64 KB
  __shared__ float Kt[256][64];                   // 64 KB PV K-tile / redO
  __shared__ float Qs[8][64];                     // 2 KB
  __shared__ float a04[64];
  __shared__ float qas[8];
  __shared__ float msh[8], invs[8];
  __shared__ float red[8][8];                     // [row][wave]
  __shared__ unsigned long long mask_lds[8][32];  // 2 KB adjacency bitmask

  const int t    = threadIdx.x;
  const int lane = t & 63;
  const int wv   = t >> 6;       // 0..7
  const int i0   = blockIdx.x * 8;

  // ---- adjacency bitmask, once per block: wave wv owns row wv ----
  for (int c = 0; c < 32; ++c) {
    const float ad = adj[(size_t)(i0 + wv) * N_NODES + c * 64 + lane];
    const unsigned long long b = __ballot(ad > 0.f);
    if (lane == 0) mask_lds[wv][c] = b;
  }

  for (int hh = 0; hh < HEADS; ++hh) {
    __syncthreads();   // prev head fully done with e_lds/Qs/Kt (covers mask stage)
    Qs[t >> 6][t & 63] = Qw[((size_t)hh * N_NODES + i0 + (t >> 6)) * HD + (t & 63)];
    if (t < 64) a04[t] = 0.4f * a[hh * HD + t];
    if (t < 8)  qas[t] = qaw[hh * N_NODES + i0 + t];
    __syncthreads();

    // ========== pass 1: e + per-row running max (1 K-row/thread) ==========
    float m[8];
    #pragma unroll
    for (int r = 0; r < 8; ++r) m[r] = -3e38f;

    for (int jp = 0; jp < 4; ++jp) {
      const int j0 = t + jp * 512;            // this thread's j
      const float* __restrict__ Kp = Kw + ((size_t)hh * N_NODES + j0) * HD;
      float acc[8] = {};
      #pragma unroll
      for (int fc = 0; fc < 16; ++fc) {
        const int f = fc << 2;
        const float4 kva = *(const float4*)&Kp[f];       // lane-consecutive rows
        const float4 av  = *(const float4*)&a04[f];      // broadcast
        #pragma unroll
        for (int r = 0; r < 8; ++r) {
          const float4 qv = *(const float4*)&Qs[r][f];   // broadcast
          acc[r] = fmaf(fabsf(qv.x + kva.x), av.x, acc[r]);
          acc[r] = fmaf(fabsf(qv.y + kva.y), av.y, acc[r]);
          acc[r] = fmaf(fabsf(qv.z + kva.z), av.z, acc[r]);
          acc[r] = fmaf(fabsf(qv.w + kva.w), av.w, acc[r]);
        }
      }
      const float kaj = kaw[hh * N_NODES + j0];
      const int c = j0 >> 6, b = j0 & 63;
      #pragma unroll
      for (int r = 0; r < 8; ++r) {
        const float e = ((mask_lds[r][c] >> b) & 1ull)
                            ? acc[r] + qas[r] + kaj : -1e30f;
        e_lds[r][j0] = e;
        m[r] = fmaxf(m[r], e);
      }
    }
    #pragma unroll
    for (int r = 0; r < 8; ++r) {
      float v = m[r];
      #pragma unroll
      for (int off = 32; off; off >>= 1) v = fmaxf(v, __shfl_xor(v, off));
      if (lane == 0) red[r][wv] = v;
    }
    __syncthreads();
    if (t < 8) {
      float v = red[t][0];
      #pragma unroll
      for (int q = 1; q < 8; ++q) v = fmaxf(v, red[t][q]);
      msh[t] = v;
    }
    __syncthreads();

    // ================= pass 2a: exp in place + row sums =================
    float s[8];
    #pragma unroll
    for (int r = 0; r < 8; ++r) s[r] = 0.f;
    #pragma unroll
    for (int jp = 0; jp < 2; ++jp) {
      const int j0 = 2 * t + jp * 1024;
      #pragma unroll
      for (int r = 0; r < 8; ++r) {
        const float2 v = *(const float2*)&e_lds[r][j0];
        const float mr = msh[r];
        const float p0 = __expf(v.x - mr);
        const float p1 = __expf(v.y - mr);
        *(float2*)&e_lds[r][j0] = make_float2(p0, p1);
        s[r] += p0 + p1;
      }
    }
    #pragma unroll
    for (int r = 0; r < 8; ++r) {
      float v = s[r];
      #pragma unroll
      for (int off = 32; off; off >>= 1) v += __shfl_xor(v, off);
      if (lane == 0) red[r][wv] = v;
    }
    __syncthreads();
    if (t < 8) {
      float v = red[t][0];
      #pragma unroll
      for (int q = 1; q < 8; ++q) v += red[t][q];
      invs[t] = 1.0f / v;
    }
    __syncthreads();   // invs + all p visible block-wide

    // ================= attn_mean RMW (own slots) =================
    #pragma unroll
    for (int jp = 0; jp < 2; ++jp) {
      const int j0 = 2 * t + jp * 1024;
      #pragma unroll
      for (int r = 0; r < 8; ++r) {
        const float2 v = *(const float2*)&e_lds[r][j0];
        const float iv = invs[r];
        float2 p = make_float2(v.x * iv, v.y * iv);
        float2* ap = (float2*)&out_attn[(size_t)(i0 + r) * N_NODES + j0];
        if (hh == 0) {
          *ap = p;
        } else if (hh == HEADS - 1) {
          const float2 po = *ap;
          *ap = make_float2((po.x + p.x) * (1.0f / 6.0f),
                            (po.y + p.y) * (1.0f / 6.0f));
        } else {
          const float2 po = *ap;
          *ap = make_float2(po.x + p.x, po.y + p.y);
        }
      }
    }

    // ================= PV: LDS-tiled K, wave j-slices =================
    float po[8] = {};
    for (int jt = 0; jt < 8; ++jt) {
      const int j0 = jt << 8;                // tile = 256 rows
      __syncthreads();                       // prev tile reads of Kt done
      #pragma unroll
      for (int q = 0; q < 8; ++q) {          // stage 256x64 = 4096 float4s
        const int idx = t + (q << 9);
        const int row = idx >> 4, c = (idx & 15) << 2;
        *(float4*)&Kt[row][c] =
            *(const float4*)&Kw[((size_t)hh * N_NODES + j0 + row) * HD + c];
      }
      __syncthreads();
      // wave wv covers local rows [wv*32, wv*32+32) for ALL 8 output rows
      #pragma unroll 2
      for (int jc = 0; jc < 32; jc += 4) {
        const int jl = (wv << 5) + jc;       // local row in Kt
        const int jg = j0 + jl;              // global j (uniform per wave)
        float pq[8][4];
        #pragma unroll
        for (int r = 0; r < 8; ++r) {        // uniform b128 broadcasts
          const float4 v = *(const float4*)&e_lds[r][jg];
          pq[r][0] = v.x; pq[r][1] = v.y; pq[r][2] = v.z; pq[r][3] = v.w;
        }
        #pragma unroll
        for (int u = 0; u < 4; ++u) {
          const float kv = Kt[jl + u][lane]; // along-row b32, conflict-free
          #pragma unroll
          for (int r = 0; r < 8; ++r)
            po[r] = fmaf(pq[r][u], kv, po[r]);
        }
      }
    }
    // cross-wave O reduce through reused Kt space: redO[wave][row][f]
    float* redO = &Kt[0][0];
    __syncthreads();                         // PV reads of Kt done
    #pragma unroll
    for (int r = 0; r < 8; ++r) redO[((wv << 3) + r) * 64 + lane] = po[r];
    __syncthreads();
    {
      const int r = t >> 6, f = t & 63;      // r == wv, f == lane
      float sum = 0.f;
      #pragma unroll
      for (int w = 0; w < 8; ++w) sum += redO[((w << 3) + r) * 64 + f];
      out_h[(size_t)(i0 + r) * OUT_DIM + hh * HD + f] =
          sum * invs[r] + bias[hh * HD + f];
    }
  }
}

}  // namespace

// ---------------------------------------------------------------------------
extern "C" void kernel_launch(void* const* d_in, const int* in_sizes, int n_in,
                              void* d_out, int out_size, void* d_ws, size_t ws_size,
                              hipStream_t stream) {
  const float* hmat = (const float*)d_in[0];
  const float* adj  = (const float*)d_in[1];
  const float* Wsrc = (const float*)d_in[2];
  const float* Wdst = (const float*)d_in[3];
  const float* a    = (const float*)d_in[4];
  const float* bias = (const float*)d_in[5];

  float* out_h    = (float*)d_out;                        // 2048 x 384
  float* out_attn = out_h + (size_t)N_NODES * OUT_DIM;    // 2048 x 2048

  float* Qw  = (float*)d_ws;                              // [6][2048][64]
  float* Kw  = Qw + (size_t)HEADS * N_NODES * HD;         // [6][2048][64]
  float* qaw = Kw + (size_t)HEADS * N_NODES * HD;         // [6][2048]
  float* kaw = qaw + HEADS * N_NODES;                     // [6][2048]

  qk_proj<<<dim3(N_NODES / 4, HEADS, 2), 256, 0, stream>>>(hmat, Wsrc, Wdst, a,
                                                           Qw, Kw, qaw, kaw);
  gat_fused<<<dim3(N_NODES / 8), 512, 0, stream>>>(Qw, Kw, qaw, kaw, a, adj,
                                                   bias, out_h, out_attn);
}

// Round 9
// 1224.094 us; speedup vs baseline: 4.3219x; 4.3219x over previous
//
#include <hip/hip_runtime.h>

namespace {

constexpr int N_NODES = 2048;
constexpr int IN_DIM  = 256;
constexpr int HEADS   = 6;
constexpr int HD      = 64;
constexpr int OUT_DIM = HEADS * HD;   // 384
constexpr int ROWS    = 4;            // rows per block

// ---------------------------------------------------------------------------
// Kernel 1: projections + attention-vector dots. (unchanged; never a top cost)
// ---------------------------------------------------------------------------
__global__ __launch_bounds__(256) void qk_proj(
    const float* __restrict__ hmat, const float* __restrict__ Wsrc,
    const float* __restrict__ Wdst, const float* __restrict__ a,
    float* __restrict__ Qw, float* __restrict__ Kw,
    float* __restrict__ qaw, float* __restrict__ kaw)
{
  const int lane = threadIdx.x & 63;
  const int w    = threadIdx.x >> 6;
  const int i    = blockIdx.x * 4 + w;
  const int head = blockIdx.y;
  const int z    = blockIdx.z;
  const float* __restrict__ W = (z ? Wdst : Wsrc) + (size_t)head * IN_DIM * HD;
  const float* __restrict__ hrow = hmat + (size_t)i * IN_DIM;

  float a0 = 0.f, a1 = 0.f, a2 = 0.f, a3 = 0.f;
  #pragma unroll 4
  for (int k = 0; k < IN_DIM; k += 4) {
    const float4 hv = *(const float4*)&hrow[k];
    a0 = fmaf(hv.x, W[(k + 0) * HD + lane], a0);
    a1 = fmaf(hv.y, W[(k + 1) * HD + lane], a1);
    a2 = fmaf(hv.z, W[(k + 2) * HD + lane], a2);
    a3 = fmaf(hv.w, W[(k + 3) * HD + lane], a3);
  }
  const float acc = (a0 + a1) + (a2 + a3);
  (z ? Kw : Qw)[((size_t)head * N_NODES + i) * HD + lane] = acc;

  float rsum = acc * a[head * HD + lane];
  #pragma unroll
  for (int off = 32; off; off >>= 1) rsum += __shfl_xor(rsum, off);
  if (lane == 0) (z ? kaw : qaw)[head * N_NODES + i] = 0.6f * rsum;
}

// ---------------------------------------------------------------------------
// Kernel 2: fused scores + masked softmax + attn_mean + PV + h'.
// Round-3 skeleton (the only structure with sane measured HBM traffic:
// 100 MB fetch / 101 MB write) with its measured limiters fixed:
//  * 4 rows/block, grid 512, 256 thr (4 waves), LDS 72.5 KB -> 2 blocks/CU
//    (round 3 was 1 block/CU at 99 KB).
//  * deferred softmax via e_lds[4][2048]: e computed ONCE (round 3 did 2x).
//  * Kt[128][65] row-major: eacc reads (lane=j, stride 65==1 mod 32) and
//    PV reads (lane=f, consecutive) both conflict-free b32.
//  * attn_mean accumulated in 32 regs across heads, written once at the end
//    (no global RMW; statically indexed -> no scratch).
//  * K is ONLY consumed via LDS tiles staged with coalesced float4 reads.
// ---------------------------------------------------------------------------
__global__ __launch_bounds__(256, 2) void gat_fused(
    const float* __restrict__ Qw, const float* __restrict__ Kw,
    const float* __restrict__ qaw, const float* __restrict__ kaw,
    const float* __restrict__ a, const float* __restrict__ adj,
    const float* __restrict__ bias, float* __restrict__ out_h,
    float* __restrict__ out_attn)
{
  __shared__ float e_lds[ROWS][N_NODES];           // 32 KB
  __shared__ float Kt[128][65];                    // 33.3 KB
  __shared__ float Qs[ROWS][64];                   // 1 KB
  __shared__ float a04[64];
  __shared__ float qas[ROWS];
  __shared__ float msh[ROWS], invs[ROWS];
  __shared__ float red[ROWS][4];                   // [row][wave]
  __shared__ float redO[4][ROWS][64];              // 4 KB PV cross-wave
  __shared__ unsigned long long mask_lds[ROWS][32];// 1 KB adjacency bitmask

  const int t    = threadIdx.x;
  const int lane = t & 63;
  const int wv   = t >> 6;            // 0..3
  const int i0   = blockIdx.x * ROWS;

  // ---- adjacency bitmask, once per block: wave wv owns row wv ----
  for (int c = 0; c < 32; ++c) {
    const float ad = adj[(size_t)(i0 + wv) * N_NODES + c * 64 + lane];
    const unsigned long long b = __ballot(ad > 0.f);
    if (lane == 0) mask_lds[wv][c] = b;
  }

  float attn_acc[ROWS][8] = {};       // [row][jp*2+{0,1}] static-indexed

  auto stageKt = [&](int hh, int j0) {
    #pragma unroll
    for (int q = 0; q < 8; ++q) {     // 128 rows x 64 f
      const int idx = t + (q << 8);
      const int row = idx >> 4, c = (idx & 15) << 2;
      const float4 v = *(const float4*)&Kw[((size_t)hh * N_NODES + j0 + row) * HD + c];
      Kt[row][c] = v.x; Kt[row][c + 1] = v.y; Kt[row][c + 2] = v.z; Kt[row][c + 3] = v.w;
    }
  };

  const int rg = t >> 7;              // row-group 0..1 (2 waves each)
  const int jl = t & 127;             // j within tile
  const int r0 = rg << 1;

  for (int hh = 0; hh < HEADS; ++hh) {
    __syncthreads();                  // prev head done with e_lds/Qs/Kt/redO
    if (t < ROWS * 64) Qs[t >> 6][t & 63] =
        Qw[((size_t)hh * N_NODES + i0 + (t >> 6)) * HD + (t & 63)];
    if (t < 64) a04[t] = 0.4f * a[hh * HD + t];
    if (t < ROWS) qas[t] = qaw[hh * N_NODES + i0 + t];
    __syncthreads();

    // ============ pass 1: e (once) + per-row running max ============
    float m0 = -3e38f, m1 = -3e38f;
    for (int jt = 0; jt < 16; ++jt) {
      const int j0 = jt << 7;
      __syncthreads();                // prior tile eacc reads done
      stageKt(hh, j0);
      __syncthreads();
      const float kaj = kaw[hh * N_NODES + j0 + jl];
      float acc0 = 0.f, acc1 = 0.f;
      #pragma unroll
      for (int f0 = 0; f0 < 64; f0 += 4) {
        const float4 av = *(const float4*)&a04[f0];
        const float4 q0 = *(const float4*)&Qs[r0 + 0][f0];    // broadcast
        const float4 q1 = *(const float4*)&Qs[r0 + 1][f0];    // broadcast
        const float k0 = Kt[jl][f0 + 0], k1 = Kt[jl][f0 + 1]; // b32 x4,
        const float k2 = Kt[jl][f0 + 2], k3 = Kt[jl][f0 + 3]; // conflict-free
        acc0 = fmaf(fabsf(q0.x + k0), av.x, acc0);
        acc0 = fmaf(fabsf(q0.y + k1), av.y, acc0);
        acc0 = fmaf(fabsf(q0.z + k2), av.z, acc0);
        acc0 = fmaf(fabsf(q0.w + k3), av.w, acc0);
        acc1 = fmaf(fabsf(q1.x + k0), av.x, acc1);
        acc1 = fmaf(fabsf(q1.y + k1), av.y, acc1);
        acc1 = fmaf(fabsf(q1.z + k2), av.z, acc1);
        acc1 = fmaf(fabsf(q1.w + k3), av.w, acc1);
      }
      const int jg = j0 + jl;
      const int c = jg >> 6, b = jg & 63;
      const float e0 = ((mask_lds[r0 + 0][c] >> b) & 1ull)
                           ? acc0 + qas[r0 + 0] + kaj : -1e30f;
      const float e1 = ((mask_lds[r0 + 1][c] >> b) & 1ull)
                           ? acc1 + qas[r0 + 1] + kaj : -1e30f;
      e_lds[r0 + 0][jg] = e0;
      e_lds[r0 + 1][jg] = e1;
      m0 = fmaxf(m0, e0);
      m1 = fmaxf(m1, e1);
    }
    #pragma unroll
    for (int off = 32; off; off >>= 1) {
      m0 = fmaxf(m0, __shfl_xor(m0, off));
      m1 = fmaxf(m1, __shfl_xor(m1, off));
    }
    if (lane == 0) { red[r0 + 0][wv] = m0; red[r0 + 1][wv] = m1; }
    __syncthreads();
    if (t < ROWS) {                   // row t computed by waves {2*(t>>1), +1}
      const int wb = (t >> 1) << 1;
      msh[t] = fmaxf(red[t][wb], red[t][wb + 1]);
    }
    __syncthreads();

    // ============ pass 2a: exp in place (own slots) + row sums ============
    float s0 = 0.f, s1 = 0.f, s2 = 0.f, s3 = 0.f;
    #pragma unroll
    for (int jp = 0; jp < 4; ++jp) {
      const int j0s = (jp << 9) + 2 * t;
      {
        const float2 v = *(const float2*)&e_lds[0][j0s];
        const float p0 = __expf(v.x - msh[0]), p1 = __expf(v.y - msh[0]);
        *(float2*)&e_lds[0][j0s] = make_float2(p0, p1); s0 += p0 + p1;
      }
      {
        const float2 v = *(const float2*)&e_lds[1][j0s];
        const float p0 = __expf(v.x - msh[1]), p1 = __expf(v.y - msh[1]);
        *(float2*)&e_lds[1][j0s] = make_float2(p0, p1); s1 += p0 + p1;
      }
      {
        const float2 v = *(const float2*)&e_lds[2][j0s];
        const float p0 = __expf(v.x - msh[2]), p1 = __expf(v.y - msh[2]);
        *(float2*)&e_lds[2][j0s] = make_float2(p0, p1); s2 += p0 + p1;
      }
      {
        const float2 v = *(const float2*)&e_lds[3][j0s];
        const float p0 = __expf(v.x - msh[3]), p1 = __expf(v.y - msh[3]);
        *(float2*)&e_lds[3][j0s] = make_float2(p0, p1); s3 += p0 + p1;
      }
    }
    #pragma unroll
    for (int off = 32; off; off >>= 1) {
      s0 += __shfl_xor(s0, off); s1 += __shfl_xor(s1, off);
      s2 += __shfl_xor(s2, off); s3 += __shfl_xor(s3, off);
    }
    if (lane == 0) {
      red[0][wv] = s0; red[1][wv] = s1; red[2][wv] = s2; red[3][wv] = s3;
    }
    __syncthreads();
    if (t < ROWS)
      invs[t] = 1.0f / (red[t][0] + red[t][1] + red[t][2] + red[t][3]);
    __syncthreads();

    // ============ attn_mean accumulate in registers (own slots) ============
    #pragma unroll
    for (int jp = 0; jp < 4; ++jp) {
      const int j0s = (jp << 9) + 2 * t;
      #pragma unroll
      for (int r = 0; r < ROWS; ++r) {
        const float2 v = *(const float2*)&e_lds[r][j0s];
        attn_acc[r][jp * 2 + 0] = fmaf(v.x, invs[r], attn_acc[r][jp * 2 + 0]);
        attn_acc[r][jp * 2 + 1] = fmaf(v.y, invs[r], attn_acc[r][jp * 2 + 1]);
      }
    }

    // ============ PV: restage Kt; wave wv owns j-subrange of tile ============
    float po0 = 0.f, po1 = 0.f, po2 = 0.f, po3 = 0.f;
    for (int jt = 0; jt < 16; ++jt) {
      const int j0 = jt << 7;
      __syncthreads();                // prev tile PV / pass2a-attn reads done
      stageKt(hh, j0);
      __syncthreads();
      #pragma unroll 2
      for (int jc = 0; jc < 32; jc += 4) {
        const int jl2 = (wv << 5) + jc;
        const int jg = j0 + jl2;
        const float4 p0v = *(const float4*)&e_lds[0][jg];   // broadcasts
        const float4 p1v = *(const float4*)&e_lds[1][jg];
        const float4 p2v = *(const float4*)&e_lds[2][jg];
        const float4 p3v = *(const float4*)&e_lds[3][jg];
        {
          const float kv = Kt[jl2 + 0][lane];               // consecutive lanes
          po0 = fmaf(p0v.x, kv, po0); po1 = fmaf(p1v.x, kv, po1);
          po2 = fmaf(p2v.x, kv, po2); po3 = fmaf(p3v.x, kv, po3);
        }
        {
          const float kv = Kt[jl2 + 1][lane];
          po0 = fmaf(p0v.y, kv, po0); po1 = fmaf(p1v.y, kv, po1);
          po2 = fmaf(p2v.y, kv, po2); po3 = fmaf(p3v.y, kv, po3);
        }
        {
          const float kv = Kt[jl2 + 2][lane];
          po0 = fmaf(p0v.z, kv, po0); po1 = fmaf(p1v.z, kv, po1);
          po2 = fmaf(p2v.z, kv, po2); po3 = fmaf(p3v.z, kv, po3);
        }
        {
          const float kv = Kt[jl2 + 3][lane];
          po0 = fmaf(p0v.w, kv, po0); po1 = fmaf(p1v.w, kv, po1);
          po2 = fmaf(p2v.w, kv, po2); po3 = fmaf(p3v.w, kv, po3);
        }
      }
    }
    __syncthreads();
    redO[wv][0][lane] = po0; redO[wv][1][lane] = po1;
    redO[wv][2][lane] = po2; redO[wv][3][lane] = po3;
    __syncthreads();
    {
      const int r = t >> 6, f = lane;
      const float sum = redO[0][r][f] + redO[1][r][f] +
                        redO[2][r][f] + redO[3][r][f];
      out_h[(size_t)(i0 + r) * OUT_DIM + hh * HD + f] =
          sum * invs[r] + bias[hh * HD + f];
    }
  }

  // ============ final attn_mean write (once) ============
  #pragma unroll
  for (int jp = 0; jp < 4; ++jp) {
    const int j0s = (jp << 9) + 2 * t;
    #pragma unroll
    for (int r = 0; r < ROWS; ++r) {
      *(float2*)&out_attn[(size_t)(i0 + r) * N_NODES + j0s] =
          make_float2(attn_acc[r][jp * 2 + 0] * (1.0f / 6.0f),
                      attn_acc[r][jp * 2 + 1] * (1.0f / 6.0f));
    }
  }
}

}  // namespace

// ---------------------------------------------------------------------------
extern "C" void kernel_launch(void* const* d_in, const int* in_sizes, int n_in,
                              void* d_out, int out_size, void* d_ws, size_t ws_size,
                              hipStream_t stream) {
  const float* hmat = (const float*)d_in[0];
  const float* adj  = (const float*)d_in[1];
  const float* Wsrc = (const float*)d_in[2];
  const float* Wdst = (const float*)d_in[3];
  const float* a    = (const float*)d_in[4];
  const float* bias = (const float*)d_in[5];

  float* out_h    = (float*)d_out;                        // 2048 x 384
  float* out_attn = out_h + (size_t)N_NODES * OUT_DIM;    // 2048 x 2048

  float* Qw  = (float*)d_ws;                              // [6][2048][64]
  float* Kw  = Qw + (size_t)HEADS * N_NODES * HD;         // [6][2048][64]
  float* qaw = Kw + (size_t)HEADS * N_NODES * HD;         // [6][2048]
  float* kaw = qaw + HEADS * N_NODES;                     // [6][2048]

  qk_proj<<<dim3(N_NODES / 4, HEADS, 2), 256, 0, stream>>>(hmat, Wsrc, Wdst, a,
                                                           Qw, Kw, qaw, kaw);
  gat_fused<<<dim3(N_NODES / ROWS), 256, 0, stream>>>(Qw, Kw, qaw, kaw, a, adj,
                                                      bias, out_h, out_attn);
}